// Round 4
// baseline (324.859 us; speedup 1.0000x reference)
//
#include <hip/hip_runtime.h>

// Reverb: y[o, y, x] = sum_c conv[c,o] * x[c,y,x] * Wsum[c,y,x]
//   Wsum[c,y,x] = sum_{i,j in 3x3, bounds} weight[c*9 + i*3 + j, (y+1-i)*256 + (x+1-j)]
// Memory-bound: weight 151MB read-once dominates. Fused single kernel.

#define SS 256
#define CH 64
#define LL (SS * SS)

__global__ __launch_bounds__(256, 2) void reverb_fused(
    const float* __restrict__ xin,   // (64, 256, 256)
    const float* __restrict__ w,     // (576, 65536)
    const float* __restrict__ conv,  // (64, 64)  [c][o]
    float* __restrict__ out)         // (64, 256, 256)
{
    __shared__ float h2[CH][128];    // 32 KB: h2 for this (y, x-half)
    __shared__ float cv[CH][CH];     // 16 KB: conv staged

    const int t  = threadIdx.x;
    const int b  = blockIdx.x;       // 0..511
    const int y  = b >> 1;           // output row
    const int xh = (b & 1) << 7;     // x-half offset: 0 or 128

    // ---- stage conv into LDS (4096 floats, float4 x4 per thread)
    {
        const float4* g4 = reinterpret_cast<const float4*>(conv);
        float4* s4 = reinterpret_cast<float4*>(&cv[0][0]);
#pragma unroll
        for (int k = 0; k < 4; ++k)
            s4[k * 256 + t] = g4[k * 256 + t];
    }

    // ---- phase 1: h2[c][xl] = x[c,y,xg] * Wsum
    const int xl = t & 127;          // local x within half
    const int xg = xh + xl;          // global x
    const int c0 = (t >> 7) << 5;    // 0 or 32: channel half

#pragma unroll 4
    for (int cc = 0; cc < 32; ++cc) {
        const int c = c0 + cc;
        const float xv = xin[(size_t)c * LL + y * SS + xg];
        float s = 0.0f;
        const float* wc = w + (size_t)c * 9 * LL;
#pragma unroll
        for (int i = 0; i < 3; ++i) {
            const int row = y + 1 - i;
            if ((unsigned)row < (unsigned)SS) {
                const float* wr = wc + (size_t)(i * 3) * LL + (size_t)row * SS;
                // j=0: col = xg+1 ; j=1: col = xg ; j=2: col = xg-1
                if (xg < SS - 1) s += wr[xg + 1];
                s += wr[LL + xg];
                if (xg > 0)      s += wr[2 * LL + xg - 1];
            }
        }
        h2[c][xl] = xv * s;
    }
    __syncthreads();

    // ---- phase 2: out[o0+oo, y, xh+x0+k] = sum_c cv[c][o] * h2[c][x]
    const int x0 = (t & 31) << 2;    // 0..124, float4 along x
    const int o0 = (t >> 5) << 3;    // 0..56, 8 outputs along o

    float4 acc[8];
#pragma unroll
    for (int oo = 0; oo < 8; ++oo) acc[oo] = make_float4(0.f, 0.f, 0.f, 0.f);

#pragma unroll
    for (int c = 0; c < CH; ++c) {
        const float4 hv = *reinterpret_cast<const float4*>(&h2[c][x0]);
        const float4 ca = *reinterpret_cast<const float4*>(&cv[c][o0]);
        const float4 cb = *reinterpret_cast<const float4*>(&cv[c][o0 + 4]);
        float cw[8] = {ca.x, ca.y, ca.z, ca.w, cb.x, cb.y, cb.z, cb.w};
#pragma unroll
        for (int oo = 0; oo < 8; ++oo) {
            acc[oo].x += cw[oo] * hv.x;
            acc[oo].y += cw[oo] * hv.y;
            acc[oo].z += cw[oo] * hv.z;
            acc[oo].w += cw[oo] * hv.w;
        }
    }

    float* op = out + (size_t)o0 * LL + (size_t)y * SS + xh + x0;
#pragma unroll
    for (int oo = 0; oo < 8; ++oo)
        *reinterpret_cast<float4*>(op + (size_t)oo * LL) = acc[oo];
}

extern "C" void kernel_launch(void* const* d_in, const int* in_sizes, int n_in,
                              void* d_out, int out_size, void* d_ws, size_t ws_size,
                              hipStream_t stream) {
    const float* x    = (const float*)d_in[0];  // (1,64,256,256)
    const float* w    = (const float*)d_in[1];  // (1,576,65536)
    const float* conv = (const float*)d_in[2];  // (64,64)
    float* out        = (float*)d_out;          // (1,64,256,256)

    reverb_fused<<<dim3(512), dim3(256), 0, stream>>>(x, w, conv, out);
}

// Round 5
// 250.527 us; speedup vs baseline: 1.2967x; 1.2967x over previous
//
#include <hip/hip_runtime.h>

// Reverb: y[o,y,x] = sum_c conv[c,o] * x[c,y,x] * Wsum[c,y,x]
//   Wsum[c,y,x] = sum_{i,j in 3x3, bounds} weight[c*9+i*3+j, (y+1-i)*256 + (x+1-j)]
// Latency-bound fix: whole-row blocks, float4 weight loads (1KB/wave-instr),
// +-1 taps via __shfl (lane edges == image boundary -> zero).

#define SS 256
#define CH 64
#define LL (SS * SS)

__global__ __launch_bounds__(256, 1) void reverb_fused(
    const float* __restrict__ xin,   // (64, 256, 256)
    const float* __restrict__ w,     // (576, 65536)
    const float* __restrict__ conv,  // (64, 64)  [c][o]
    float* __restrict__ out)         // (64, 256, 256)
{
    __shared__ float h2[CH][SS];     // 64 KB: one full row, all channels
    __shared__ float cv[CH][CH];     // 16 KB

    const int t    = threadIdx.x;
    const int y    = blockIdx.x;     // 0..255: output row
    const int lane = t & 63;
    const int wv   = t >> 6;         // wave 0..3

    // ---- stage conv (4096 floats, float4 x4 per thread)
    {
        const float4* g4 = reinterpret_cast<const float4*>(conv);
        float4* s4 = reinterpret_cast<float4*>(&cv[0][0]);
#pragma unroll
        for (int k = 0; k < 4; ++k)
            s4[k * 256 + t] = g4[k * 256 + t];
    }

    // ---- phase 1: wave covers full row (4 px/lane), 16 channels per wave
    const int px = lane << 2;        // 0..252
#pragma unroll 4
    for (int cc = 0; cc < 16; ++cc) {
        const int c = wv * 16 + cc;
        const float4 xv = *reinterpret_cast<const float4*>(
            xin + (size_t)c * LL + (size_t)y * SS + px);
        float s0 = 0.f, s1 = 0.f, s2 = 0.f, s3 = 0.f;
        const float* wc = w + (size_t)c * 9 * LL;
#pragma unroll
        for (int i = 0; i < 3; ++i) {
            const int r = y + 1 - i;
            if ((unsigned)r < (unsigned)SS) {
                const float* base = wc + (size_t)(i * 3) * LL + (size_t)r * SS + px;
                const float4 v0 = *reinterpret_cast<const float4*>(base);          // j=0: col=p+1
                const float4 v1 = *reinterpret_cast<const float4*>(base + LL);     // j=1: col=p
                const float4 v2 = *reinterpret_cast<const float4*>(base + 2 * LL); // j=2: col=p-1
                // j=1 (middle)
                s0 += v1.x; s1 += v1.y; s2 += v1.z; s3 += v1.w;
                // j=0: pixel p=4L+m takes elem m+1; m=3 takes next lane's .x
                float nx = __shfl_down(v0.x, 1);
                if (lane == 63) nx = 0.f;   // col 256: out of image
                s0 += v0.y; s1 += v0.z; s2 += v0.w; s3 += nx;
                // j=2: pixel p takes elem m-1; m=0 takes prev lane's .w
                float pv = __shfl_up(v2.w, 1);
                if (lane == 0) pv = 0.f;    // col -1: out of image
                s0 += pv; s1 += v2.x; s2 += v2.y; s3 += v2.z;
            }
        }
        float4 hr;
        hr.x = xv.x * s0; hr.y = xv.y * s1; hr.z = xv.z * s2; hr.w = xv.w * s3;
        *reinterpret_cast<float4*>(&h2[c][px]) = hr;
    }
    __syncthreads();

    // ---- phase 2: out[o, y, x] = sum_c cv[c][o] * h2[c][x]
    const int o0 = (t >> 5) << 3;    // 0..56, 8 outputs per thread
    const int x0 = (t & 31) << 2;    // 0..124 (+ second half at x0+128)

    float4 accA[8], accB[8];
#pragma unroll
    for (int oo = 0; oo < 8; ++oo) {
        accA[oo] = make_float4(0.f, 0.f, 0.f, 0.f);
        accB[oo] = make_float4(0.f, 0.f, 0.f, 0.f);
    }

#pragma unroll 8
    for (int c = 0; c < CH; ++c) {
        const float4 ha = *reinterpret_cast<const float4*>(&h2[c][x0]);
        const float4 hb = *reinterpret_cast<const float4*>(&h2[c][x0 + 128]);
        const float4 ca = *reinterpret_cast<const float4*>(&cv[c][o0]);
        const float4 cb = *reinterpret_cast<const float4*>(&cv[c][o0 + 4]);
        const float cw[8] = {ca.x, ca.y, ca.z, ca.w, cb.x, cb.y, cb.z, cb.w};
#pragma unroll
        for (int oo = 0; oo < 8; ++oo) {
            accA[oo].x += cw[oo] * ha.x;
            accA[oo].y += cw[oo] * ha.y;
            accA[oo].z += cw[oo] * ha.z;
            accA[oo].w += cw[oo] * ha.w;
            accB[oo].x += cw[oo] * hb.x;
            accB[oo].y += cw[oo] * hb.y;
            accB[oo].z += cw[oo] * hb.z;
            accB[oo].w += cw[oo] * hb.w;
        }
    }

    float* op = out + (size_t)o0 * LL + (size_t)y * SS;
#pragma unroll
    for (int oo = 0; oo < 8; ++oo) {
        *reinterpret_cast<float4*>(op + (size_t)oo * LL + x0)       = accA[oo];
        *reinterpret_cast<float4*>(op + (size_t)oo * LL + x0 + 128) = accB[oo];
    }
}

extern "C" void kernel_launch(void* const* d_in, const int* in_sizes, int n_in,
                              void* d_out, int out_size, void* d_ws, size_t ws_size,
                              hipStream_t stream) {
    const float* x    = (const float*)d_in[0];  // (1,64,256,256)
    const float* w    = (const float*)d_in[1];  // (1,576,65536)
    const float* conv = (const float*)d_in[2];  // (64,64)
    float* out        = (float*)d_out;          // (1,64,256,256)

    reverb_fused<<<dim3(256), dim3(256), 0, stream>>>(x, w, conv, out);
}

// Round 6
// 232.521 us; speedup vs baseline: 1.3971x; 1.0774x over previous
//
#include <hip/hip_runtime.h>

// Reverb: y[o,y,x] = sum_c conv[c,o] * x[c,y,x] * Wsum[c,y,x]
//   Wsum[c,y,x] = sum_{i,j in 3x3, bounds} weight[c*9+i*3+j, (y+1-i)*256 + (x+1-j)]
// Round 5 was occupancy-capped (1 blk/CU x 4 waves). Same structure, 1024
// threads: 16 waves/CU, float4 weight loads, shfl for +-1 taps.

#define SS 256
#define CH 64
#define LL (SS * SS)

__global__ __launch_bounds__(1024, 4) void reverb_fused(
    const float* __restrict__ xin,   // (64, 256, 256)
    const float* __restrict__ w,     // (576, 65536)
    const float* __restrict__ conv,  // (64, 64)  [c][o]
    float* __restrict__ out)         // (64, 256, 256)
{
    __shared__ float h2[CH][SS];     // 64 KB: one full row, all channels
    __shared__ float cv[CH][CH];     // 16 KB

    const int t    = threadIdx.x;    // 0..1023
    const int y    = blockIdx.x;     // 0..255: output row
    const int lane = t & 63;
    const int wv   = t >> 6;         // wave 0..15

    // ---- stage conv (4096 floats = 1024 x float4)
    reinterpret_cast<float4*>(&cv[0][0])[t] =
        reinterpret_cast<const float4*>(conv)[t];

    // ---- phase 1: each wave covers the full row (4 px/lane), 4 channels
    const int px = lane << 2;        // 0..252
#pragma unroll
    for (int cc = 0; cc < 4; ++cc) {
        const int c = (wv << 2) + cc;
        const float4 xv = *reinterpret_cast<const float4*>(
            xin + (size_t)c * LL + (size_t)y * SS + px);
        float s0 = 0.f, s1 = 0.f, s2 = 0.f, s3 = 0.f;
        const float* wc = w + (size_t)c * 9 * LL;
#pragma unroll
        for (int i = 0; i < 3; ++i) {
            const int r = y + 1 - i;
            if ((unsigned)r < (unsigned)SS) {
                const float* base = wc + (size_t)(i * 3) * LL + (size_t)r * SS + px;
                const float4 v0 = *reinterpret_cast<const float4*>(base);          // j=0: col=p+1
                const float4 v1 = *reinterpret_cast<const float4*>(base + LL);     // j=1: col=p
                const float4 v2 = *reinterpret_cast<const float4*>(base + 2 * LL); // j=2: col=p-1
                // j=1 (middle)
                s0 += v1.x; s1 += v1.y; s2 += v1.z; s3 += v1.w;
                // j=0: pixel p takes elem m+1; m=3 takes next lane's .x
                float nx = __shfl_down(v0.x, 1);
                if (lane == 63) nx = 0.f;   // col 256: out of image
                s0 += v0.y; s1 += v0.z; s2 += v0.w; s3 += nx;
                // j=2: pixel p takes elem m-1; m=0 takes prev lane's .w
                float pv = __shfl_up(v2.w, 1);
                if (lane == 0) pv = 0.f;    // col -1: out of image
                s0 += pv; s1 += v2.x; s2 += v2.y; s3 += v2.z;
            }
        }
        float4 hr;
        hr.x = xv.x * s0; hr.y = xv.y * s1; hr.z = xv.z * s2; hr.w = xv.w * s3;
        *reinterpret_cast<float4*>(&h2[c][px]) = hr;
    }
    __syncthreads();

    // ---- phase 2: out[o, y, x] = sum_c cv[c][o] * h2[c][x]
    //      thread: 4 o (o0..o0+3) x 4 px (p4..p4+3)
    const int p4 = (t & 63) << 2;    // 0..252
    const int o0 = (t >> 6) << 2;    // 0..60

    float4 acc[4];
#pragma unroll
    for (int oo = 0; oo < 4; ++oo) acc[oo] = make_float4(0.f, 0.f, 0.f, 0.f);

#pragma unroll 8
    for (int c = 0; c < CH; ++c) {
        const float4 hv = *reinterpret_cast<const float4*>(&h2[c][p4]);
        const float4 cw = *reinterpret_cast<const float4*>(&cv[c][o0]);
        acc[0].x += cw.x * hv.x; acc[0].y += cw.x * hv.y;
        acc[0].z += cw.x * hv.z; acc[0].w += cw.x * hv.w;
        acc[1].x += cw.y * hv.x; acc[1].y += cw.y * hv.y;
        acc[1].z += cw.y * hv.z; acc[1].w += cw.y * hv.w;
        acc[2].x += cw.z * hv.x; acc[2].y += cw.z * hv.y;
        acc[2].z += cw.z * hv.z; acc[2].w += cw.z * hv.w;
        acc[3].x += cw.w * hv.x; acc[3].y += cw.w * hv.y;
        acc[3].z += cw.w * hv.z; acc[3].w += cw.w * hv.w;
    }

    float* op = out + (size_t)o0 * LL + (size_t)y * SS + p4;
#pragma unroll
    for (int oo = 0; oo < 4; ++oo)
        *reinterpret_cast<float4*>(op + (size_t)oo * LL) = acc[oo];
}

extern "C" void kernel_launch(void* const* d_in, const int* in_sizes, int n_in,
                              void* d_out, int out_size, void* d_ws, size_t ws_size,
                              hipStream_t stream) {
    const float* x    = (const float*)d_in[0];  // (1,64,256,256)
    const float* w    = (const float*)d_in[1];  // (1,576,65536)
    const float* conv = (const float*)d_in[2];  // (64,64)
    float* out        = (float*)d_out;          // (1,64,256,256)

    reverb_fused<<<dim3(256), dim3(1024), 0, stream>>>(x, w, conv, out);
}